// Round 1
// baseline (15231.190 us; speedup 1.0000x reference)
//
#include <hip/hip_runtime.h>
#include <stdint.h>

#define TIME_STEPS 4096
#define DIM        2048
#define NWG        128
#define NTH        256
#define NB         8            // activation ring depth (power of 2)
#define LDS_PITCH  132          // 128 + 4 pad to break bank conflicts

// d_ws layout:
//   [0, NB*DIM*8)            tagged activation ring: u64 = (gen+1)<<32 | f32 bits
//   [NB*DIM*8, +NWG*4)       progress[wg] = (last staged gen) + 1

__global__ __launch_bounds__(NTH, 1) void ctrnn_kernel(
    const float* __restrict__ x,        // [TIME, DIM]
    const float* __restrict__ W,        // [DIM, DIM] row-major
    const float* __restrict__ bias,     // [DIM]
    const float* __restrict__ initial,  // [DIM]
    float* __restrict__ out,            // [TIME, DIM]
    unsigned long long* __restrict__ actbuf,
    unsigned int* __restrict__ progress)
{
  const int wg  = blockIdx.x;
  const int tid = threadIdx.x;
  const int s   = tid & 15;      // k-slice index (0..15), 128 k's each
  const int r   = tid >> 4;      // row within WG (0..15)
  const int j   = wg * 16 + r;   // global output row
  const bool owner = (s == 0);

  __shared__ float act_lds[16 * LDS_PITCH];

  // W[j][s*128 .. s*128+127] held in registers for the whole kernel.
  float4 wreg[32];
  {
    const float4* wrow = reinterpret_cast<const float4*>(W + (size_t)j * DIM + s * 128);
    #pragma unroll
    for (int i = 0; i < 32; ++i) wreg[i] = wrow[i];
  }

  const float bj = bias[j];
  float v  = initial[j];
  float xv = x[j];               // x[0][j]

  // Prologue: out[0] = initial, publish act gen 0 (tag hi = 1).
  if (owner) {
    out[j] = v;
    const float a0 = 1.0f / (1.0f + __expf(-(v + bj)));
    const unsigned long long tag0 =
        (1ull << 32) | (unsigned long long)__float_as_uint(a0);
    __hip_atomic_store(&actbuf[j], tag0, __ATOMIC_RELAXED, __HIP_MEMORY_SCOPE_AGENT);
  }

  unsigned prog_seen = 0;  // verified lower bound on min(progress[])

  for (int t = 0; t < TIME_STEPS - 1; ++t) {
    // Prefetch next input a full step early (hidden under poll+compute).
    float xn = 0.0f;
    if (owner) xn = x[(size_t)(t + 1) * DIM + j];

    // ---- poll tagged activations of gen t (this thread's 8 entries) ----
    const unsigned long long* src = actbuf + (size_t)(t & (NB - 1)) * DIM + tid * 8;
    const unsigned needtag = (unsigned)(t + 1);
    float av[8];
    unsigned pend = 0xFFu;
    do {
      #pragma unroll
      for (int i = 0; i < 8; ++i) {
        if (pend & (1u << i)) {
          const unsigned long long e =
              __hip_atomic_load(&src[i], __ATOMIC_RELAXED, __HIP_MEMORY_SCOPE_AGENT);
          if ((unsigned)(e >> 32) >= needtag) {
            av[i] = __uint_as_float((unsigned)(e & 0xFFFFFFFFull));
            pend &= ~(1u << i);
          }
        }
      }
    } while (pend);

    __syncthreads();  // all waves: prev-iter LDS reads done AND this-iter polls done

    if (tid == 0)
      __hip_atomic_store(&progress[wg], (unsigned)(t + 1),
                         __ATOMIC_RELAXED, __HIP_MEMORY_SCOPE_AGENT);

    // Stage into padded LDS: entry k = tid*8+i -> slice tid>>4, m=(tid&15)*8+i
    {
      float* dst = &act_lds[(tid >> 4) * LDS_PITCH + (tid & 15) * 8];
      #pragma unroll
      for (int i = 0; i < 8; ++i) dst[i] = av[i];
    }
    __syncthreads();

    // ---- partial dot: f_partial = sum_{k in slice s} W[j,k]*a[k] ----
    float4 acc = {0.f, 0.f, 0.f, 0.f};
    const float* abase = &act_lds[s * LDS_PITCH];
    #pragma unroll
    for (int i = 0; i < 32; ++i) {
      const float4 a4 = *reinterpret_cast<const float4*>(abase + i * 4);
      acc.x = fmaf(wreg[i].x, a4.x, acc.x);
      acc.y = fmaf(wreg[i].y, a4.y, acc.y);
      acc.z = fmaf(wreg[i].z, a4.z, acc.z);
      acc.w = fmaf(wreg[i].w, a4.w, acc.w);
    }
    float p = (acc.x + acc.y) + (acc.z + acc.w);
    // reduce across the 16 consecutive lanes of this row
    p += __shfl_xor(p, 1, 64);
    p += __shfl_xor(p, 2, 64);
    p += __shfl_xor(p, 4, 64);
    p += __shfl_xor(p, 8, 64);

    float anew = 0.0f;
    if (owner) {
      v = 0.9f * v + 0.1f * (p + xv);
      xv = xn;
      out[(size_t)(t + 1) * DIM + j] = v;
      anew = 1.0f / (1.0f + __expf(-(v + bj)));
    }

    // ---- WAR gate: before writing gen t+1 over ring slot of gen t+1-NB,
    //      all WGs must have staged gen t+1-NB (progress >= t-6). ----
    if (t >= NB - 1) {
      const unsigned need = (unsigned)(t + 1 - (NB - 1));
      if (prog_seen < need) {
        const int lane = tid & 63;
        for (;;) {
          const unsigned a = __hip_atomic_load(&progress[lane],
                                               __ATOMIC_RELAXED, __HIP_MEMORY_SCOPE_AGENT);
          const unsigned b = __hip_atomic_load(&progress[lane + 64],
                                               __ATOMIC_RELAXED, __HIP_MEMORY_SCOPE_AGENT);
          const unsigned mn = a < b ? a : b;
          if (__all(mn >= (unsigned)(t + 1))) { prog_seen = (unsigned)(t + 1); break; }
          if (__all(mn >= need))              { prog_seen = need;              break; }
        }
      }
    }
    asm volatile("" ::: "memory");

    // ---- publish act gen t+1 (tag hi = t+2), single 8B atomic per row ----
    if (owner) {
      const unsigned long long tag =
          ((unsigned long long)(unsigned)(t + 2) << 32) |
          (unsigned long long)__float_as_uint(anew);
      __hip_atomic_store(&actbuf[(size_t)((t + 1) & (NB - 1)) * DIM + j], tag,
                         __ATOMIC_RELAXED, __HIP_MEMORY_SCOPE_AGENT);
    }
  }
}

extern "C" void kernel_launch(void* const* d_in, const int* in_sizes, int n_in,
                              void* d_out, int out_size, void* d_ws, size_t ws_size,
                              hipStream_t stream) {
  const float* x       = (const float*)d_in[0];
  const float* W       = (const float*)d_in[1];
  const float* bias    = (const float*)d_in[2];
  const float* initial = (const float*)d_in[3];
  float* out           = (float*)d_out;

  unsigned long long* actbuf = (unsigned long long*)d_ws;
  unsigned int* progress     = (unsigned int*)((char*)d_ws + (size_t)NB * DIM * 8);

  // Ring tags + progress must start at 0 every call (ws is not re-poisoned
  // between replays; tags are generation counters).
  hipMemsetAsync(d_ws, 0, (size_t)NB * DIM * 8 + NWG * 4, stream);

  void* args[] = { (void*)&x, (void*)&W, (void*)&bias, (void*)&initial,
                   (void*)&out, (void*)&actbuf, (void*)&progress };
  hipLaunchCooperativeKernel((void*)ctrnn_kernel, dim3(NWG), dim3(NTH),
                             args, 0, stream);
}